// Round 11
// baseline (604.474 us; speedup 1.0000x reference)
//
#include <hip/hip_runtime.h>
#include <math.h>

// ---------------------------------------------------------------------------
// CamembertLayer forward, bf16-MFMA, round 16.
// B=4 S=2048 H=1024 NH=16 HD=64 FF=4096
//
// Changes vs round 15 (bgemm only; flash/LN/casts frozen at r15 best):
//  - bgemm goes 4-wave -> 8-wave (512 threads) on the SAME 128x128 tile and
//    SAME 3-buffer/48KB/counted-vmcnt skeleton. Per-wave output 64x32
//    (2 frags, 4 MFMA/step, 6 ds_read/step); resident waves/CU double
//    (3 blocks x 8 = 24 vs 12). All big kernels measured ~520TF with no
//    pipe >67% and waves ~serial -> latency/TLP-bound; TLP-per-block is the
//    one axis not yet tried. Especially rescues W2: its 512-block grid was
//    hard-capped at 8 waves/CU, now 16.
//  - staging map byte-identical (512 chunks = 1/thread now); vmcnt counts
//    scale 4->2 (stage = 2 loads/thread).
//
// Workspace (MB):
//   0: Xb bf16 (16) -> x1b after QKV | 16: Wqt,Wkt,Wvt (6) -> W1t (8)
//   24: W2t (8) | 32: q(16) k(16) vt(16) -> inter (64: 32..96)
//   80: ctx f32 (32) | 96: bcat(12KB)+vsum(16KB) -> out2 f32 (32)
//   128: x1 f32 (32).  Total 160 MB.
// ---------------------------------------------------------------------------

#define H_   1024
#define NH_  16
#define HD_  64
#define FF_  4096
#define S_   2048
#define B_   4
#define BS_  (B_ * S_)

#define EPI_NONE 0
#define EPI_GELU 1
#define EPI_QKV3 2

typedef unsigned short ushort_t;
typedef short v8s __attribute__((ext_vector_type(8)));
typedef float v4f __attribute__((ext_vector_type(4)));
typedef float v16f __attribute__((ext_vector_type(16)));

#define CQ_ 0.18033688011112042f   // log2(e)/8, folded into q

__device__ __forceinline__ unsigned short f2bf(float f) {
    union { float f; unsigned int u; } v; v.f = f;
    unsigned int u = v.u;
    return (unsigned short)((u + 0x7fffu + ((u >> 16) & 1u)) >> 16);  // RNE
}
__device__ __forceinline__ float bf2f(unsigned short h) {
    union { unsigned int u; float f; } v; v.u = ((unsigned int)h) << 16;
    return v.f;
}

// pack 2 f32 -> bf16x2 in one instruction (no builtin on gfx950)
__device__ __forceinline__ unsigned cvt_pk_bf16(float lo, float hi) {
    unsigned r;
    asm("v_cvt_pk_bf16_f32 %0, %1, %2" : "=v"(r) : "v"(lo), "v"(hi));
    return r;
}
// swap upper 32 lanes of a with lower 32 lanes of b (both updated)
__device__ __forceinline__ void pl32_swap(unsigned &a, unsigned &b) {
    asm("v_permlane32_swap_b32 %0, %1" : "+v"(a), "+v"(b));
}

typedef __attribute__((address_space(1))) void gvoid;
typedef __attribute__((address_space(3))) void lvoid;
__device__ __forceinline__ void async16(const void* g, void* l) {
    __builtin_amdgcn_global_load_lds((gvoid*)g, (lvoid*)l, 16, 0, 0);
}

// tanh-form GELU: max |delta| vs exact erf-gelu <= ~5e-4 (<< bf16 ulp there)
__device__ __forceinline__ float gelu_fast(float x) {
    const float x2 = x * x;
    const float w  = fmaf(x2, 0.044715f, 1.0f);
    const float e  = __builtin_exp2f(x * w * -2.3022083f);  // 2*sqrt(2/pi)*log2e
    return x * __builtin_amdgcn_rcpf(1.0f + e);
}

// ---------------------------------------------------------------------------
__global__ __launch_bounds__(256)
void cast_bf16_kernel(const float* __restrict__ x, ushort_t* __restrict__ y)
{
    const size_t i = ((size_t)blockIdx.x * 256 + threadIdx.x) * 4;
    float4 v = *(const float4*)&x[i];
    ushort4 o;
    o.x = f2bf(v.x); o.y = f2bf(v.y); o.z = f2bf(v.z); o.w = f2bf(v.w);
    *(ushort4*)&y[i] = o;
}

// W fp32 [K][N] -> Wt bf16 [N][K].  grid(N/32, K/32).
__global__ __launch_bounds__(256)
void cast_transpose_kernel(const float* __restrict__ W, ushort_t* __restrict__ Wt,
                           int K, int N)
{
    __shared__ float tile[32][33];
    const int tid = threadIdx.x;
    const int n0 = blockIdx.x * 32, k0 = blockIdx.y * 32;
    const int r  = tid >> 3;
    const int c4 = (tid & 7) * 4;
    float4 v = *(const float4*)&W[(size_t)(k0 + r) * N + n0 + c4];
    tile[r][c4 + 0] = v.x; tile[r][c4 + 1] = v.y;
    tile[r][c4 + 2] = v.z; tile[r][c4 + 3] = v.w;
    __syncthreads();
    ushort4 o;
    o.x = f2bf(tile[c4 + 0][r]); o.y = f2bf(tile[c4 + 1][r]);
    o.z = f2bf(tile[c4 + 2][r]); o.w = f2bf(tile[c4 + 3][r]);
    *(ushort4*)&Wt[(size_t)(n0 + r) * K + k0 + c4] = o;
}

// bcat = [bq | bk | bv]
__global__ __launch_bounds__(256)
void concat3_kernel(const float* __restrict__ a, const float* __restrict__ b,
                    const float* __restrict__ c, float* __restrict__ o)
{
    const int i = blockIdx.x * 256 + threadIdx.x;   // 0..3071
    o[i] = (i < 1024) ? a[i] : (i < 2048) ? b[i - 1024] : c[i - 2048];
}

// ---------------------------------------------------------------------------
// bf16 MFMA GEMM: C = A[M,lda] @ Bt[N,ldb]^T + bias.  512 threads.
// 128x128 tile, BK=32, 8 waves (2M x 4N), per-wave 64x32 via 2x1 frags.
// 3-buffer pipeline: stage t+2 / compute t / lgkmcnt(0)+vmcnt(2)+barrier.
// Natural block order (all grids have gx%8==0 -> per-XCD B-residency free).
// ---------------------------------------------------------------------------
template <int EPI>
__global__ __launch_bounds__(512)
void bgemm_kernel(const ushort_t* __restrict__ A, const ushort_t* __restrict__ Bt,
                  const float* __restrict__ bias, void* __restrict__ Cout,
                  int M, int N, int K, int lda, int ldb)
{
    __shared__ ushort_t Atile[3 * 128 * 32];
    __shared__ ushort_t Btile[3 * 128 * 32];

    const int tid  = threadIdx.x;
    const int wave = tid >> 6;      // 0..7
    const int lane = tid & 63;
    const int m    = lane & 31;     // 32x32 frag row / C col
    const int hi   = lane >> 5;     // k-half selector
    const int wm   = wave >> 2;     // M-half (0..1)
    const int wn   = wave & 3;      // N-quadrant (0..3)
    const int blockM = blockIdx.y * 128;
    const int blockN = blockIdx.x * 128;

    v16f acc[2];
    acc[0] = (v16f)0.f;
    acc[1] = (v16f)0.f;

    // stage one 128x32 K-tile of A and B into buffer `buf` (1 chunk/thread).
    // 16B slot pre-swizzled: global slot = (chunk&3) ^ ((row>>1)^(row>>3))&3.
    auto stage = [&](int buf, int ktile) {
        const int kt = ktile * 32;
        const int row = tid >> 2;                 // 0..127
        const int g   = (tid & 3) ^ (((row >> 1) ^ (row >> 3)) & 3);
        async16(A  + (size_t)(blockM + row) * lda + kt + g * 8,
                &Atile[buf * 4096 + tid * 8]);
        async16(Bt + (size_t)(blockN + row) * ldb + kt + g * 8,
                &Btile[buf * 4096 + tid * 8]);
    };

    // read swizzle: row = (mult of 32) + m -> sw depends only on m
    const int sw = ((m >> 1) ^ (m >> 3)) & 3;
    auto compute = [&](int buf) {
        v8s af[2][2], bfr[2];   // [k-half w][M-frag f] / [k-half w]
#pragma unroll
        for (int w = 0; w < 2; ++w) {
            const int slot = ((w * 2 + hi) ^ sw) * 8;
#pragma unroll
            for (int f = 0; f < 2; ++f)
                af[w][f] = *(const v8s*)&Atile[buf * 4096 + (wm * 64 + f * 32 + m) * 32 + slot];
            bfr[w] = *(const v8s*)&Btile[buf * 4096 + (wn * 32 + m) * 32 + slot];
        }
        __builtin_amdgcn_s_setprio(1);
#pragma unroll
        for (int w = 0; w < 2; ++w)
#pragma unroll
            for (int f = 0; f < 2; ++f)
                acc[f] = __builtin_amdgcn_mfma_f32_32x32x16_bf16(
                    af[w][f], bfr[w], acc[f], 0, 0, 0);
        __builtin_amdgcn_s_setprio(0);
    };

    const int NT = K >> 5;   // >= 32 for all call sites

    // prologue: tiles 0,1 in flight (4 loads); wait tile 0 (leave tile 1's 2).
    stage(0, 0);
    stage(1, 1);
    asm volatile("s_waitcnt vmcnt(2)" ::: "memory");
    __builtin_amdgcn_s_barrier();
    __builtin_amdgcn_sched_barrier(0);

    int bc = 0, bs = 2;
    for (int t = 0; t < NT; ++t) {
        const bool more = (t + 2 < NT);
        if (more) {
            stage(bs, t + 2);
            bs = (bs == 2) ? 0 : bs + 1;
        }
        compute(bc);
        bc = (bc == 2) ? 0 : bc + 1;
        if (t < NT - 1) {
            // own ds_reads retired (overwrite safety), then tile t+1 landed
            // (counted: tile t+2's 2 loads stay in flight).
            asm volatile("s_waitcnt lgkmcnt(0)" ::: "memory");
            if (more) asm volatile("s_waitcnt vmcnt(2)" ::: "memory");
            else      asm volatile("s_waitcnt vmcnt(0)" ::: "memory");
            __builtin_amdgcn_s_barrier();
            __builtin_amdgcn_sched_barrier(0);
        }
    }

    // epilogue. 32x32 C layout: col = lane&31, row = (reg&3) + 8*(reg>>2) + 4*hi
    const int n  = blockN + wn * 32 + m;
    const float bn = bias[n];
#pragma unroll
    for (int f = 0; f < 2; ++f) {
        if (EPI == EPI_QKV3) {
            const int nn = n & 1023;
            const int hh = nn >> 6, dd = nn & 63;
            ushort_t* base = (ushort_t*)Cout + (size_t)(n >> 10) * ((size_t)BS_ * H_);
            if (n < 2048) {
                // q/k: [bh][s][d]; q pre-scaled by log2(e)/8 for the flash exp2
                const float sc = (n < 1024) ? CQ_ : 1.f;
#pragma unroll
                for (int g = 0; g < 4; ++g)
#pragma unroll
                    for (int rr = 0; rr < 4; ++rr) {
                        const int mr = blockM + wm * 64 + f * 32 + g * 8 + hi * 4 + rr;
                        base[(((size_t)((mr >> 11) * NH_ + hh)) * S_ + (mr & 2047)) * HD_ + dd]
                            = f2bf((acc[f][g * 4 + rr] + bn) * sc);
                    }
            } else {
                // v^T: [bh][d][s], 4 consecutive s -> packed ushort4
#pragma unroll
                for (int g = 0; g < 4; ++g) {
                    const int m0 = blockM + wm * 64 + f * 32 + g * 8 + hi * 4;
                    ushort4 pk;
                    pk.x = f2bf(acc[f][g * 4 + 0] + bn);
                    pk.y = f2bf(acc[f][g * 4 + 1] + bn);
                    pk.z = f2bf(acc[f][g * 4 + 2] + bn);
                    pk.w = f2bf(acc[f][g * 4 + 3] + bn);
                    *(ushort4*)&base[(((size_t)((m0 >> 11) * NH_ + hh)) * HD_ + dd) * S_
                                     + (m0 & 2047)] = pk;
                }
            }
        } else {
#pragma unroll
            for (int g = 0; g < 4; ++g)
#pragma unroll
                for (int rr = 0; rr < 4; ++rr) {
                    const int mr = blockM + wm * 64 + f * 32 + g * 8 + hi * 4 + rr;
                    const float v = acc[f][g * 4 + rr] + bn;
                    if (EPI == EPI_GELU) {
                        ((ushort_t*)Cout)[(size_t)mr * N + n] = f2bf(gelu_fast(v));
                    } else {
                        ((float*)Cout)[(size_t)mr * N + n] = v;
                    }
                }
        }
    }
}

// ---------------------------------------------------------------------------
// vsum[bh][d] = sum_s V^T[bh][d][s]  (contiguous row sums)
// ---------------------------------------------------------------------------
__global__ __launch_bounds__(256)
void vsum_kernel(const ushort_t* __restrict__ VT, float* __restrict__ vsum)
{
    const int bh   = blockIdx.x;
    const int tid  = threadIdx.x;
    const int d    = tid >> 2;
    const int part = tid & 3;
    const ushort_t* p = VT + (size_t)bh * HD_ * S_ + (size_t)d * S_ + part * 512;
    float acc = 0.f;
    for (int i = 0; i < 512; i += 4) {
        ushort4 u = *(const ushort4*)&p[i];
        acc += (bf2f(u.x) + bf2f(u.y)) + (bf2f(u.z) + bf2f(u.w));
    }
    acc += __shfl_xor(acc, 1);
    acc += __shfl_xor(acc, 2);
    if (part == 0) vsum[bh * HD_ + d] = acc;
}

// ---------------------------------------------------------------------------
// Flash attention, 32x32x16 MFMA, max-free softmax, in-register P^T.
// grid(1024 = 16 q-tiles x 64 bh), 4 waves; wave owns 32 q-cols.
// LDS union (32KB total): smem = 2 KV double-buffer slots of 16KB
// (Ks: 8KB + Vs: 8KB each). Q tile is staged into slot 1, read into
// registers at t=0, then slot 1 is reused as the second KV buffer.
// (exact r11 kernel: 127us, VGPR 80)
// ---------------------------------------------------------------------------
__global__ __launch_bounds__(256)
void flash_kernel(const ushort_t* __restrict__ Q, const ushort_t* __restrict__ Kg,
                  const ushort_t* __restrict__ VT, const float* __restrict__ vsum,
                  float* __restrict__ ctx)
{
    __shared__ ushort_t smem[16384];   // 32 KB

    // XCD swizzle: 1024 blocks % 8 == 0 -> 8 consecutive bh per XCD (~4MB K/V = L2)
    int wg = blockIdx.x;
    wg = (wg & 7) * 128 + (wg >> 3);
    const int bh = wg >> 4;
    const int q0 = (wg & 15) * 128;

    const int tid  = threadIdx.x;
    const int wave = tid >> 6;
    const int lane = tid & 63;
    const int m    = lane & 31;   // A-frag row / B-frag (q) col / C col
    const int hi   = lane >> 5;   // k-half selector

    const ushort_t* Qp = Q  + (size_t)bh * S_ * HD_ + (size_t)q0 * HD_;
    const ushort_t* Kp = Kg + (size_t)bh * S_ * HD_;
    const ushort_t* Vp = VT + (size_t)bh * HD_ * S_;

    ushort_t* Qs = &smem[8192];   // aliases KV buffer 1 (dead after qf reads)

    // stage one 64-key K/V tile into buffer `buf` (4 loads/thread)
    auto stageKV = [&](int buf, int t) {
        const int kv0 = t * 64;
        ushort_t* Ksb = &smem[buf * 8192];
        ushort_t* Vsb = &smem[buf * 8192 + 4096];
#pragma unroll
        for (int i = 0; i < 2; ++i) {
            const int ch = i * 256 + tid;
            const int row = ch >> 3, c = ch & 7;
            async16(Kp + (size_t)(kv0 + row) * HD_ + ((c ^ (row & 7)) * 8),
                    &Ksb[ch * 8]);
            async16(Vp + (size_t)row * S_ + kv0 + ((c ^ (row & 7)) * 8),
                    &Vsb[ch * 8]);
        }
    };

    // prologue: Q tile (4 loads) into slot 1 + K/V tile 0 into slot 0.
#pragma unroll
    for (int i = 0; i < 4; ++i) {
        const int ch = i * 256 + tid;
        const int row = ch >> 3, c = ch & 7;
        async16(Qp + (size_t)row * HD_ + ((c ^ (row & 7)) * 8), &Qs[ch * 8]);
    }
    stageKV(0, 0);
    asm volatile("s_waitcnt vmcnt(0)" ::: "memory");
    __builtin_amdgcn_s_barrier();
    __builtin_amdgcn_sched_barrier(0);

    // Q fragments into registers; then release the Qs region for KV buffer 1.
    v8s qf[4];
    {
        const int qrow = wave * 32 + m;
#pragma unroll
        for (int c = 0; c < 4; ++c)
            qf[c] = *(const v8s*)&Qs[qrow * 64 + (((2 * c + hi) ^ (qrow & 7)) * 8)];
    }
    asm volatile("s_waitcnt lgkmcnt(0)" ::: "memory");
    __builtin_amdgcn_s_barrier();
    __builtin_amdgcn_sched_barrier(0);

    v16f o0 = (v16f)0.f, o1 = (v16f)0.f;
    float lp0 = 0.f, lp1 = 0.f, lp2 = 0.f, lp3 = 0.f;
    v8s pf[4];

    const int NT = S_ / 64;
    for (int t = 0; t < NT; ++t) {
        const int b = t & 1;
        if (t + 1 < NT) stageKV(b ^ 1, t + 1);   // overlapped with compute below
        const ushort_t* Ksb = &smem[b * 8192];
        const ushort_t* Vsb = &smem[b * 8192 + 4096];

        // per 32-key block: S^T = K Q^T, p = exp2(s), pack+swap into pf
#pragma unroll
        for (int a = 0; a < 2; ++a) {
            v16f z = (v16f)0.f;
            const int krow = a * 32 + m;
#pragma unroll
            for (int c = 0; c < 4; ++c) {
                v8s kf = *(const v8s*)&Ksb[krow * 64 + (((2 * c + hi) ^ (m & 7)) * 8)];
                z = __builtin_amdgcn_mfma_f32_32x32x16_bf16(kf, qf[c], z, 0, 0, 0);
            }
            unsigned u[8];
#pragma unroll
            for (int mm = 0; mm < 8; ++mm) {
                const float plo = __builtin_exp2f(z[2 * mm]);
                const float phi = __builtin_exp2f(z[2 * mm + 1]);
                if ((mm & 3) == 0)      lp0 += plo + phi;
                else if ((mm & 3) == 1) lp1 += plo + phi;
                else if ((mm & 3) == 2) lp2 += plo + phi;
                else                    lp3 += plo + phi;
                u[mm] = cvt_pk_bf16(plo, phi);
            }
            // rows {0,1,8,9}+4hi / {2,3,10,11}+4hi -> keys 8hi+{0..7} of chunk 2a
            pl32_swap(u[0], u[2]); pl32_swap(u[1], u[3]);
            // rows {16,17,24,25}+4hi / ... -> chunk 2a+1
            pl32_swap(u[4], u[6]); pl32_swap(u[5], u[7]);
            union { unsigned w[4]; v8s s; } c0, c1;
            c0.w[0] = u[0]; c0.w[1] = u[1]; c0.w[2] = u[2]; c0.w[3] = u[3];
            c1.w[0] = u[4]; c1.w[1] = u[5]; c1.w[2] = u[6]; c1.w[3] = u[7];
            pf[2 * a]     = c0.s;
            pf[2 * a + 1] = c1.s;
        }

        // O^T += V^T P^T
#pragma unroll
        for (int c = 0; c < 4; ++c) {
            const int sw = ((2 * c + hi) ^ (m & 7)) * 8;
            v8s vf0 = *(const v8s*)&Vsb[m * 64 + sw];
            v8s vf1 = *(const v8s*)&Vsb[(32 + m) * 64 + sw];
            o0 = __builtin_amdgcn_mfma_f32_32x32x16_bf16(vf0, pf[c], o0, 0, 0, 0);
            o1 = __builtin_amdgcn_mfma_f32_32x32x16_bf16(vf1, pf[c], o1, 0, 0, 0);
        }

        // my ds_reads of buffer b retired; tile t+1 landed; release b for t+2.
        asm volatile("s_waitcnt lgkmcnt(0)" ::: "memory");
        asm volatile("s_waitcnt vmcnt(0)" ::: "memory");
        __builtin_amdgcn_s_barrier();
        __builtin_amdgcn_sched_barrier(0);
    }

    // l: lane covers half the keys for its q; partner is lane^32
    float l_r = (lp0 + lp1) + (lp2 + lp3);
    l_r += __shfl_xor(l_r, 32);
    const float linv = 1.f / l_r;

    // epilogue: lane owns q = q0 + wave*32 + m; d = g*32 + rq*8 + hi*4 + i
    const int bb = bh >> 4, hh = bh & 15;
    const int srow = q0 + wave * 32 + m;
    float* cp = ctx + ((size_t)(bb * S_ + srow)) * H_ + hh * HD_;
#pragma unroll
    for (int g = 0; g < 2; ++g) {
        const v16f& o = g ? o1 : o0;
#pragma unroll
        for (int rq = 0; rq < 4; ++rq) {
            const int d0 = g * 32 + rq * 8 + hi * 4;
            float4 vs4 = *(const float4*)&vsum[bh * HD_ + d0];
            float4 ov;
            ov.x = o[rq * 4 + 0] * linv + 1e-9f * vs4.x;
            ov.y = o[rq * 4 + 1] * linv + 1e-9f * vs4.y;
            ov.z = o[rq * 4 + 2] * linv + 1e-9f * vs4.z;
            ov.w = o[rq * 4 + 3] * linv + 1e-9f * vs4.w;
            *(float4*)&cp[d0] = ov;
        }
    }
}

// ---------------------------------------------------------------------------
template <bool WB>
__global__ __launch_bounds__(256)
void add_ln_kernel(const float* __restrict__ A, const float* __restrict__ Bv,
                   const float* __restrict__ gamma, const float* __restrict__ beta,
                   float* __restrict__ out, ushort_t* __restrict__ outb)
{
    const int row = blockIdx.x;
    const int tid = threadIdx.x;
    const float* a = A  + (size_t)row * H_;
    const float* b = Bv + (size_t)row * H_;

    float4 av = *(const float4*)&a[tid * 4];
    float4 bv = *(const float4*)&b[tid * 4];
    float x[4] = { av.x + bv.x, av.y + bv.y, av.z + bv.z, av.w + bv.w };

    float s  = x[0] + x[1] + x[2] + x[3];
    float s2 = x[0]*x[0] + x[1]*x[1] + x[2]*x[2] + x[3]*x[3];
#pragma unroll
    for (int off = 1; off < 64; off <<= 1) {
        s  += __shfl_xor(s,  off);
        s2 += __shfl_xor(s2, off);
    }
    __shared__ float rs[8];
    const int wave = tid >> 6, lane = tid & 63;
    if (lane == 0) { rs[wave] = s; rs[4 + wave] = s2; }
    __syncthreads();
    const float sum  = rs[0] + rs[1] + rs[2] + rs[3];
    const float sum2 = rs[4] + rs[5] + rs[6] + rs[7];
    const float mu   = sum * (1.f / H_);
    const float var  = sum2 * (1.f / H_) - mu * mu;
    const float rstd = rsqrtf(var + 1e-12f);

    float4 gv = *(const float4*)&gamma[tid * 4];
    float4 be = *(const float4*)&beta[tid * 4];
    float4 ov;
    ov.x = (x[0] - mu) * rstd * gv.x + be.x;
    ov.y = (x[1] - mu) * rstd * gv.y + be.y;
    ov.z = (x[2] - mu) * rstd * gv.z + be.z;
    ov.w = (x[3] - mu) * rstd * gv.w + be.w;
    *(float4*)&out[(size_t)row * H_ + tid * 4] = ov;
    if (WB) {
        ushort4 ob;
        ob.x = f2bf(ov.x); ob.y = f2bf(ov.y); ob.z = f2bf(ov.z); ob.w = f2bf(ov.w);
        *(ushort4*)&outb[(size_t)row * H_ + tid * 4] = ob;
    }
}

// ---------------------------------------------------------------------------
extern "C" void kernel_launch(void* const* d_in, const int* in_sizes, int n_in,
                              void* d_out, int out_size, void* d_ws, size_t ws_size,
                              hipStream_t stream)
{
    const float* hidden = (const float*)d_in[0];
    const float* Wq     = (const float*)d_in[1];
    const float* bq     = (const float*)d_in[2];
    const float* Wk     = (const float*)d_in[3];
    const float* bk     = (const float*)d_in[4];
    const float* Wv     = (const float*)d_in[5];
    const float* bv     = (const float*)d_in[6];
    const float* ln1_g  = (const float*)d_in[7];
    const float* ln1_b  = (const float*)d_in[8];
    const float* W1     = (const float*)d_in[9];
    const float* b1     = (const float*)d_in[10];
    const float* W2     = (const float*)d_in[11];
    const float* b2     = (const float*)d_in[12];
    const float* ln2_g  = (const float*)d_in[13];
    const float* ln2_b  = (const float*)d_in[14];

    char* ws = (char*)d_ws;
    const size_t MB = 1024 * 1024;
    ushort_t* Xb    = (ushort_t*)(ws + 0);
    ushort_t* x1b   = (ushort_t*)(ws + 0);
    ushort_t* Wqt   = (ushort_t*)(ws + 16 * MB);   // Wqt|Wkt|Wvt contiguous
    ushort_t* Wkt   = (ushort_t*)(ws + 18 * MB);
    ushort_t* Wvt   = (ushort_t*)(ws + 20 * MB);
    ushort_t* W1t   = (ushort_t*)(ws + 16 * MB);
    ushort_t* W2t   = (ushort_t*)(ws + 24 * MB);
    ushort_t* q     = (ushort_t*)(ws + 32 * MB);   // q|k|vt contiguous
    ushort_t* k     = (ushort_t*)(ws + 48 * MB);
    ushort_t* vt    = (ushort_t*)(ws + 64 * MB);
    float*    ctx   = (float*)(ws + 80 * MB);
    ushort_t* inter = (ushort_t*)(ws + 32 * MB);
    float*    bcat  = (float*)(ws + 96 * MB);          // dead before out2
    float*    vsum  = (float*)(ws + 96 * MB + 16384);  // dead before out2
    float*    out2  = (float*)(ws + 96 * MB);
    float*    x1    = (float*)(ws + 128 * MB);
    float*    out   = (float*)d_out;

    const dim3 blk(256);
    const dim3 blk512(512);

    // 0. casts / prep
    cast_bf16_kernel<<<dim3(BS_ * H_ / 1024), blk, 0, stream>>>(hidden, Xb);
    cast_transpose_kernel<<<dim3(32, 32),  blk, 0, stream>>>(Wq, Wqt, H_, H_);
    cast_transpose_kernel<<<dim3(32, 32),  blk, 0, stream>>>(Wk, Wkt, H_, H_);
    cast_transpose_kernel<<<dim3(32, 32),  blk, 0, stream>>>(Wv, Wvt, H_, H_);
    cast_transpose_kernel<<<dim3(32, 128), blk, 0, stream>>>(W2, W2t, FF_, H_);
    concat3_kernel<<<dim3(12), blk, 0, stream>>>(bq, bk, bv, bcat);

    // 1. fused QKV projection: [q | k | v^T], q pre-scaled by log2(e)/8
    bgemm_kernel<EPI_QKV3><<<dim3(24, 64), blk512, 0, stream>>>(
        Xb, Wqt, bcat, q, BS_, 3 * H_, H_, H_, H_);

    // 2. W1 transpose (Wqt region now free)
    cast_transpose_kernel<<<dim3(128, 32), blk, 0, stream>>>(W1, W1t, H_, FF_);

    // 3. V column sums (rows of V^T)
    vsum_kernel<<<dim3(B_ * NH_), blk, 0, stream>>>(vt, vsum);

    // 4. attention (1024 blocks = 16 q-tiles x 64 bh, XCD-swizzled)
    flash_kernel<<<dim3((S_ / 128) * (B_ * NH_)), blk, 0, stream>>>(q, k, vt, vsum, ctx);

    // 5. x1 = LN1(hidden + ctx), + bf16 copy
    add_ln_kernel<true><<<dim3(BS_), blk, 0, stream>>>(hidden, ctx, ln1_g, ln1_b, x1, x1b);

    // 6. inter = gelu(x1 @ W1 + b1) bf16
    bgemm_kernel<EPI_GELU><<<dim3(32, 64), blk512, 0, stream>>>(
        x1b, W1t, b1, inter, BS_, FF_, H_, H_, H_);

    // 7. out2 = inter @ W2 + b2 fp32
    bgemm_kernel<EPI_NONE><<<dim3(8, 64), blk512, 0, stream>>>(
        inter, W2t, b2, out2, BS_, H_, FF_, FF_, FF_);

    // 8. d_out = LN2(out2 + x1)
    add_ln_kernel<false><<<dim3(BS_), blk, 0, stream>>>(out2, x1, ln2_g, ln2_b, out, nullptr);
}

// Round 12
// 574.964 us; speedup vs baseline: 1.0513x; 1.0513x over previous
//
#include <hip/hip_runtime.h>
#include <math.h>

// ---------------------------------------------------------------------------
// CamembertLayer forward, bf16-MFMA, round 17.
// B=4 S=2048 H=1024 NH=16 HD=64 FF=4096
//
// Changes vs round 16:
//  - bgemm: REVERT to the r15 4-wave / 3-buffer / 48KB / vmcnt(4) skeleton
//    (r16's 8-wave nulled: more barrier participants, same per-step wall).
//  - bgemm micro-opt (addressing): staging via 4 per-thread pointers
//    advanced 64B per staged K-tile (stage calls are strictly in increasing
//    ktile order), replacing the per-step 64-bit recompute; LDS fragment
//    offsets precomputed once (loop-invariant) + single scalar buf*4096 add.
//    Same fix dropped flash VALU 68->57 in r12. VGPR +~8, under the 128
//    threshold; LDS/occupancy unchanged; sync structure byte-identical.
//  - flash: exact r15 (128us known-good, untouched).
//
// Workspace (MB):
//   0: Xb bf16 (16) -> x1b after QKV | 16: Wqt,Wkt,Wvt (6) -> W1t (8)
//   24: W2t (8) | 32: q(16) k(16) vt(16) -> inter (64: 32..96)
//   80: ctx f32 (32) | 96: bcat(12KB)+vsum(16KB) -> out2 f32 (32)
//   128: x1 f32 (32).  Total 160 MB.
// ---------------------------------------------------------------------------

#define H_   1024
#define NH_  16
#define HD_  64
#define FF_  4096
#define S_   2048
#define B_   4
#define BS_  (B_ * S_)

#define EPI_NONE 0
#define EPI_GELU 1
#define EPI_QKV3 2

typedef unsigned short ushort_t;
typedef short v8s __attribute__((ext_vector_type(8)));
typedef float v4f __attribute__((ext_vector_type(4)));
typedef float v16f __attribute__((ext_vector_type(16)));

#define CQ_ 0.18033688011112042f   // log2(e)/8, folded into q

__device__ __forceinline__ unsigned short f2bf(float f) {
    union { float f; unsigned int u; } v; v.f = f;
    unsigned int u = v.u;
    return (unsigned short)((u + 0x7fffu + ((u >> 16) & 1u)) >> 16);  // RNE
}
__device__ __forceinline__ float bf2f(unsigned short h) {
    union { unsigned int u; float f; } v; v.u = ((unsigned int)h) << 16;
    return v.f;
}

// pack 2 f32 -> bf16x2 in one instruction (no builtin on gfx950)
__device__ __forceinline__ unsigned cvt_pk_bf16(float lo, float hi) {
    unsigned r;
    asm("v_cvt_pk_bf16_f32 %0, %1, %2" : "=v"(r) : "v"(lo), "v"(hi));
    return r;
}
// swap upper 32 lanes of a with lower 32 lanes of b (both updated)
__device__ __forceinline__ void pl32_swap(unsigned &a, unsigned &b) {
    asm("v_permlane32_swap_b32 %0, %1" : "+v"(a), "+v"(b));
}

typedef __attribute__((address_space(1))) void gvoid;
typedef __attribute__((address_space(3))) void lvoid;
__device__ __forceinline__ void async16(const void* g, void* l) {
    __builtin_amdgcn_global_load_lds((gvoid*)g, (lvoid*)l, 16, 0, 0);
}

// tanh-form GELU: max |delta| vs exact erf-gelu <= ~5e-4 (<< bf16 ulp there)
__device__ __forceinline__ float gelu_fast(float x) {
    const float x2 = x * x;
    const float w  = fmaf(x2, 0.044715f, 1.0f);
    const float e  = __builtin_exp2f(x * w * -2.3022083f);  // 2*sqrt(2/pi)*log2e
    return x * __builtin_amdgcn_rcpf(1.0f + e);
}

// ---------------------------------------------------------------------------
__global__ __launch_bounds__(256)
void cast_bf16_kernel(const float* __restrict__ x, ushort_t* __restrict__ y)
{
    const size_t i = ((size_t)blockIdx.x * 256 + threadIdx.x) * 4;
    float4 v = *(const float4*)&x[i];
    ushort4 o;
    o.x = f2bf(v.x); o.y = f2bf(v.y); o.z = f2bf(v.z); o.w = f2bf(v.w);
    *(ushort4*)&y[i] = o;
}

// W fp32 [K][N] -> Wt bf16 [N][K].  grid(N/32, K/32).
__global__ __launch_bounds__(256)
void cast_transpose_kernel(const float* __restrict__ W, ushort_t* __restrict__ Wt,
                           int K, int N)
{
    __shared__ float tile[32][33];
    const int tid = threadIdx.x;
    const int n0 = blockIdx.x * 32, k0 = blockIdx.y * 32;
    const int r  = tid >> 3;
    const int c4 = (tid & 7) * 4;
    float4 v = *(const float4*)&W[(size_t)(k0 + r) * N + n0 + c4];
    tile[r][c4 + 0] = v.x; tile[r][c4 + 1] = v.y;
    tile[r][c4 + 2] = v.z; tile[r][c4 + 3] = v.w;
    __syncthreads();
    ushort4 o;
    o.x = f2bf(tile[c4 + 0][r]); o.y = f2bf(tile[c4 + 1][r]);
    o.z = f2bf(tile[c4 + 2][r]); o.w = f2bf(tile[c4 + 3][r]);
    *(ushort4*)&Wt[(size_t)(n0 + r) * K + k0 + c4] = o;
}

// bcat = [bq | bk | bv]
__global__ __launch_bounds__(256)
void concat3_kernel(const float* __restrict__ a, const float* __restrict__ b,
                    const float* __restrict__ c, float* __restrict__ o)
{
    const int i = blockIdx.x * 256 + threadIdx.x;   // 0..3071
    o[i] = (i < 1024) ? a[i] : (i < 2048) ? b[i - 1024] : c[i - 2048];
}

// ---------------------------------------------------------------------------
// bf16 MFMA GEMM: C = A[M,lda] @ Bt[N,ldb]^T + bias.
// 128x128 tile, BK=32, 4 waves 2x2, per-wave 64x64 via 2x2 32x32x16 frags.
// 3-buffer pipeline: stage t+2 / compute t / lgkmcnt(0)+vmcnt(4)+barrier.
// Staging via incremented per-thread pointers (stage calls are in strictly
// increasing ktile order); LDS fragment offsets precomputed once.
// ---------------------------------------------------------------------------
template <int EPI>
__global__ __launch_bounds__(256)
void bgemm_kernel(const ushort_t* __restrict__ A, const ushort_t* __restrict__ Bt,
                  const float* __restrict__ bias, void* __restrict__ Cout,
                  int M, int N, int K, int lda, int ldb)
{
    __shared__ ushort_t Atile[3 * 128 * 32];
    __shared__ ushort_t Btile[3 * 128 * 32];

    const int tid  = threadIdx.x;
    const int wave = tid >> 6;
    const int lane = tid & 63;
    const int m    = lane & 31;    // 32x32 frag row / C col
    const int hi   = lane >> 5;    // k-half selector
    const int wm   = wave >> 1, wn = wave & 1;
    const int blockM = blockIdx.y * 128;
    const int blockN = blockIdx.x * 128;

    v16f acc[2][2];
#pragma unroll
    for (int a = 0; a < 2; ++a)
#pragma unroll
        for (int b = 0; b < 2; ++b) acc[a][b] = (v16f)0.f;

    // ---- staging state: 2 chunks/thread for A and B, pointers advance one
    // K-tile (32 elems) per stage call.  16B slot pre-swizzled:
    // slot = (chunk&3) ^ ((row>>1)^(row>>3))&3 ; LDS dest linear (constant).
    const int c0 = tid, c1 = 256 + tid;
    const int r0 = c0 >> 2,        r1 = c1 >> 2;
    const int g0 = (c0 & 3) ^ (((r0 >> 1) ^ (r0 >> 3)) & 3);
    const int g1 = (c1 & 3) ^ (((r1 >> 1) ^ (r1 >> 3)) & 3);
    const ushort_t* pA0 = A  + (size_t)(blockM + r0) * lda + g0 * 8;
    const ushort_t* pA1 = A  + (size_t)(blockM + r1) * lda + g1 * 8;
    const ushort_t* pB0 = Bt + (size_t)(blockN + r0) * ldb + g0 * 8;
    const ushort_t* pB1 = Bt + (size_t)(blockN + r1) * ldb + g1 * 8;
    const int d0 = c0 * 8, d1 = c1 * 8;

    auto stage = [&]() -> void {
        // buf cycles 0,1,2 in lockstep with the caller's bs counter
        static_assert(true, "");
    };
    (void)stage;

    int stage_buf = 0;
    auto STAGE = [&]() {
        const int base = stage_buf * 4096;
        async16(pA0, &Atile[base + d0]);
        async16(pA1, &Atile[base + d1]);
        async16(pB0, &Btile[base + d0]);
        async16(pB1, &Btile[base + d1]);
        pA0 += 32; pA1 += 32; pB0 += 32; pB1 += 32;
        stage_buf = (stage_buf == 2) ? 0 : stage_buf + 1;
    };

    // ---- compute: fragment offsets are loop-invariant; only buf*4096 varies.
    const int sw = ((m >> 1) ^ (m >> 3)) & 3;
    int aoff[2][2], boff[2][2];
#pragma unroll
    for (int w = 0; w < 2; ++w) {
        const int slot = ((w * 2 + hi) ^ sw) * 8;
#pragma unroll
        for (int f = 0; f < 2; ++f) {
            aoff[w][f] = (wm * 64 + f * 32 + m) * 32 + slot;
            boff[w][f] = (wn * 64 + f * 32 + m) * 32 + slot;
        }
    }
    auto COMPUTE = [&](int buf) {
        const int base = buf * 4096;
        v8s af[2][2], bfr[2][2];   // [k-half w][frag]
#pragma unroll
        for (int w = 0; w < 2; ++w)
#pragma unroll
            for (int f = 0; f < 2; ++f) {
                af[w][f]  = *(const v8s*)&Atile[base + aoff[w][f]];
                bfr[w][f] = *(const v8s*)&Btile[base + boff[w][f]];
            }
        __builtin_amdgcn_s_setprio(1);
#pragma unroll
        for (int w = 0; w < 2; ++w)
#pragma unroll
            for (int a = 0; a < 2; ++a)
#pragma unroll
                for (int b = 0; b < 2; ++b)
                    acc[a][b] = __builtin_amdgcn_mfma_f32_32x32x16_bf16(
                        af[w][a], bfr[w][b], acc[a][b], 0, 0, 0);
        __builtin_amdgcn_s_setprio(0);
    };

    const int NT = K >> 5;   // >= 32 for all call sites

    // prologue: tiles 0,1 in flight (8 loads); wait tile 0 (leave tile 1's 4).
    STAGE();
    STAGE();
    asm volatile("s_waitcnt vmcnt(4)" ::: "memory");
    __builtin_amdgcn_s_barrier();
    __builtin_amdgcn_sched_barrier(0);

    int bc = 0;
    for (int t = 0; t < NT; ++t) {
        const bool more = (t + 2 < NT);
        if (more) STAGE();           // tile t+2 into the rotating buffer
        COMPUTE(bc);
        bc = (bc == 2) ? 0 : bc + 1;
        if (t < NT - 1) {
            // own ds_reads retired (overwrite safety), then tile t+1 landed
            // (counted: tile t+2's 4 loads stay in flight).
            asm volatile("s_waitcnt lgkmcnt(0)" ::: "memory");
            if (more) asm volatile("s_waitcnt vmcnt(4)" ::: "memory");
            else      asm volatile("s_waitcnt vmcnt(0)" ::: "memory");
            __builtin_amdgcn_s_barrier();
            __builtin_amdgcn_sched_barrier(0);
        }
    }

    // epilogue. 32x32 C layout: col = lane&31, row = (reg&3) + 8*(reg>>2) + 4*hi
#pragma unroll
    for (int im = 0; im < 2; ++im) {
#pragma unroll
        for (int in = 0; in < 2; ++in) {
            const int n  = blockN + wn * 64 + in * 32 + m;
            const float bn = bias[n];
            if (EPI == EPI_QKV3) {
                const int nn = n & 1023;
                const int hh = nn >> 6, dd = nn & 63;
                ushort_t* base = (ushort_t*)Cout + (size_t)(n >> 10) * ((size_t)BS_ * H_);
                if (n < 2048) {
                    // q/k: [bh][s][d]; q pre-scaled by log2(e)/8 for the flash exp2
                    const float sc = (n < 1024) ? CQ_ : 1.f;
#pragma unroll
                    for (int g = 0; g < 4; ++g)
#pragma unroll
                        for (int rr = 0; rr < 4; ++rr) {
                            const int mr = blockM + wm * 64 + im * 32 + g * 8 + hi * 4 + rr;
                            base[(((size_t)((mr >> 11) * NH_ + hh)) * S_ + (mr & 2047)) * HD_ + dd]
                                = f2bf((acc[im][in][g * 4 + rr] + bn) * sc);
                        }
                } else {
                    // v^T: [bh][d][s], 4 consecutive s -> packed ushort4
#pragma unroll
                    for (int g = 0; g < 4; ++g) {
                        const int m0 = blockM + wm * 64 + im * 32 + g * 8 + hi * 4;
                        ushort4 pk;
                        pk.x = f2bf(acc[im][in][g * 4 + 0] + bn);
                        pk.y = f2bf(acc[im][in][g * 4 + 1] + bn);
                        pk.z = f2bf(acc[im][in][g * 4 + 2] + bn);
                        pk.w = f2bf(acc[im][in][g * 4 + 3] + bn);
                        *(ushort4*)&base[(((size_t)((m0 >> 11) * NH_ + hh)) * HD_ + dd) * S_
                                         + (m0 & 2047)] = pk;
                    }
                }
            } else {
#pragma unroll
                for (int g = 0; g < 4; ++g)
#pragma unroll
                    for (int rr = 0; rr < 4; ++rr) {
                        const int mr = blockM + wm * 64 + im * 32 + g * 8 + hi * 4 + rr;
                        const float v = acc[im][in][g * 4 + rr] + bn;
                        if (EPI == EPI_GELU) {
                            ((ushort_t*)Cout)[(size_t)mr * N + n] = f2bf(gelu_fast(v));
                        } else {
                            ((float*)Cout)[(size_t)mr * N + n] = v;
                        }
                    }
            }
        }
    }
}

// ---------------------------------------------------------------------------
// vsum[bh][d] = sum_s V^T[bh][d][s]  (contiguous row sums)
// ---------------------------------------------------------------------------
__global__ __launch_bounds__(256)
void vsum_kernel(const ushort_t* __restrict__ VT, float* __restrict__ vsum)
{
    const int bh   = blockIdx.x;
    const int tid  = threadIdx.x;
    const int d    = tid >> 2;
    const int part = tid & 3;
    const ushort_t* p = VT + (size_t)bh * HD_ * S_ + (size_t)d * S_ + part * 512;
    float acc = 0.f;
    for (int i = 0; i < 512; i += 4) {
        ushort4 u = *(const ushort4*)&p[i];
        acc += (bf2f(u.x) + bf2f(u.y)) + (bf2f(u.z) + bf2f(u.w));
    }
    acc += __shfl_xor(acc, 1);
    acc += __shfl_xor(acc, 2);
    if (part == 0) vsum[bh * HD_ + d] = acc;
}

// ---------------------------------------------------------------------------
// Flash attention, 32x32x16 MFMA, max-free softmax, in-register P^T.
// grid(1024 = 16 q-tiles x 64 bh), 4 waves; wave owns 32 q-cols.
// LDS union (32KB total): smem = 2 KV double-buffer slots of 16KB
// (Ks: 8KB + Vs: 8KB each). Q tile is staged into slot 1, read into
// registers at t=0, then slot 1 is reused as the second KV buffer.
// (exact r11/r15 kernel: 127-128us, VGPR 80)
// ---------------------------------------------------------------------------
__global__ __launch_bounds__(256)
void flash_kernel(const ushort_t* __restrict__ Q, const ushort_t* __restrict__ Kg,
                  const ushort_t* __restrict__ VT, const float* __restrict__ vsum,
                  float* __restrict__ ctx)
{
    __shared__ ushort_t smem[16384];   // 32 KB

    // XCD swizzle: 1024 blocks % 8 == 0 -> 8 consecutive bh per XCD (~4MB K/V = L2)
    int wg = blockIdx.x;
    wg = (wg & 7) * 128 + (wg >> 3);
    const int bh = wg >> 4;
    const int q0 = (wg & 15) * 128;

    const int tid  = threadIdx.x;
    const int wave = tid >> 6;
    const int lane = tid & 63;
    const int m    = lane & 31;   // A-frag row / B-frag (q) col / C col
    const int hi   = lane >> 5;   // k-half selector

    const ushort_t* Qp = Q  + (size_t)bh * S_ * HD_ + (size_t)q0 * HD_;
    const ushort_t* Kp = Kg + (size_t)bh * S_ * HD_;
    const ushort_t* Vp = VT + (size_t)bh * HD_ * S_;

    ushort_t* Qs = &smem[8192];   // aliases KV buffer 1 (dead after qf reads)

    // stage one 64-key K/V tile into buffer `buf` (4 loads/thread)
    auto stageKV = [&](int buf, int t) {
        const int kv0 = t * 64;
        ushort_t* Ksb = &smem[buf * 8192];
        ushort_t* Vsb = &smem[buf * 8192 + 4096];
#pragma unroll
        for (int i = 0; i < 2; ++i) {
            const int ch = i * 256 + tid;
            const int row = ch >> 3, c = ch & 7;
            async16(Kp + (size_t)(kv0 + row) * HD_ + ((c ^ (row & 7)) * 8),
                    &Ksb[ch * 8]);
            async16(Vp + (size_t)row * S_ + kv0 + ((c ^ (row & 7)) * 8),
                    &Vsb[ch * 8]);
        }
    };

    // prologue: Q tile (4 loads) into slot 1 + K/V tile 0 into slot 0.
#pragma unroll
    for (int i = 0; i < 4; ++i) {
        const int ch = i * 256 + tid;
        const int row = ch >> 3, c = ch & 7;
        async16(Qp + (size_t)row * HD_ + ((c ^ (row & 7)) * 8), &Qs[ch * 8]);
    }
    stageKV(0, 0);
    asm volatile("s_waitcnt vmcnt(0)" ::: "memory");
    __builtin_amdgcn_s_barrier();
    __builtin_amdgcn_sched_barrier(0);

    // Q fragments into registers; then release the Qs region for KV buffer 1.
    v8s qf[4];
    {
        const int qrow = wave * 32 + m;
#pragma unroll
        for (int c = 0; c < 4; ++c)
            qf[c] = *(const v8s*)&Qs[qrow * 64 + (((2 * c + hi) ^ (qrow & 7)) * 8)];
    }
    asm volatile("s_waitcnt lgkmcnt(0)" ::: "memory");
    __builtin_amdgcn_s_barrier();
    __builtin_amdgcn_sched_barrier(0);

    v16f o0 = (v16f)0.f, o1 = (v16f)0.f;
    float lp0 = 0.f, lp1 = 0.f, lp2 = 0.f, lp3 = 0.f;
    v8s pf[4];

    const int NT = S_ / 64;
    for (int t = 0; t < NT; ++t) {
        const int b = t & 1;
        if (t + 1 < NT) stageKV(b ^ 1, t + 1);   // overlapped with compute below
        const ushort_t* Ksb = &smem[b * 8192];
        const ushort_t* Vsb = &smem[b * 8192 + 4096];

        // per 32-key block: S^T = K Q^T, p = exp2(s), pack+swap into pf
#pragma unroll
        for (int a = 0; a < 2; ++a) {
            v16f z = (v16f)0.f;
            const int krow = a * 32 + m;
#pragma unroll
            for (int c = 0; c < 4; ++c) {
                v8s kf = *(const v8s*)&Ksb[krow * 64 + (((2 * c + hi) ^ (m & 7)) * 8)];
                z = __builtin_amdgcn_mfma_f32_32x32x16_bf16(kf, qf[c], z, 0, 0, 0);
            }
            unsigned u[8];
#pragma unroll
            for (int mm = 0; mm < 8; ++mm) {
                const float plo = __builtin_exp2f(z[2 * mm]);
                const float phi = __builtin_exp2f(z[2 * mm + 1]);
                if ((mm & 3) == 0)      lp0 += plo + phi;
                else if ((mm & 3) == 1) lp1 += plo + phi;
                else if ((mm & 3) == 2) lp2 += plo + phi;
                else                    lp3 += plo + phi;
                u[mm] = cvt_pk_bf16(plo, phi);
            }
            // rows {0,1,8,9}+4hi / {2,3,10,11}+4hi -> keys 8hi+{0..7} of chunk 2a
            pl32_swap(u[0], u[2]); pl32_swap(u[1], u[3]);
            // rows {16,17,24,25}+4hi / ... -> chunk 2a+1
            pl32_swap(u[4], u[6]); pl32_swap(u[5], u[7]);
            union { unsigned w[4]; v8s s; } c0, c1;
            c0.w[0] = u[0]; c0.w[1] = u[1]; c0.w[2] = u[2]; c0.w[3] = u[3];
            c1.w[0] = u[4]; c1.w[1] = u[5]; c1.w[2] = u[6]; c1.w[3] = u[7];
            pf[2 * a]     = c0.s;
            pf[2 * a + 1] = c1.s;
        }

        // O^T += V^T P^T
#pragma unroll
        for (int c = 0; c < 4; ++c) {
            const int sw = ((2 * c + hi) ^ (m & 7)) * 8;
            v8s vf0 = *(const v8s*)&Vsb[m * 64 + sw];
            v8s vf1 = *(const v8s*)&Vsb[(32 + m) * 64 + sw];
            o0 = __builtin_amdgcn_mfma_f32_32x32x16_bf16(vf0, pf[c], o0, 0, 0, 0);
            o1 = __builtin_amdgcn_mfma_f32_32x32x16_bf16(vf1, pf[c], o1, 0, 0, 0);
        }

        // my ds_reads of buffer b retired; tile t+1 landed; release b for t+2.
        asm volatile("s_waitcnt lgkmcnt(0)" ::: "memory");
        asm volatile("s_waitcnt vmcnt(0)" ::: "memory");
        __builtin_amdgcn_s_barrier();
        __builtin_amdgcn_sched_barrier(0);
    }

    // l: lane covers half the keys for its q; partner is lane^32
    float l_r = (lp0 + lp1) + (lp2 + lp3);
    l_r += __shfl_xor(l_r, 32);
    const float linv = 1.f / l_r;

    // epilogue: lane owns q = q0 + wave*32 + m; d = g*32 + rq*8 + hi*4 + i
    const int bb = bh >> 4, hh = bh & 15;
    const int srow = q0 + wave * 32 + m;
    float* cp = ctx + ((size_t)(bb * S_ + srow)) * H_ + hh * HD_;
#pragma unroll
    for (int g = 0; g < 2; ++g) {
        const v16f& o = g ? o1 : o0;
#pragma unroll
        for (int rq = 0; rq < 4; ++rq) {
            const int d0 = g * 32 + rq * 8 + hi * 4;
            float4 vs4 = *(const float4*)&vsum[bh * HD_ + d0];
            float4 ov;
            ov.x = o[rq * 4 + 0] * linv + 1e-9f * vs4.x;
            ov.y = o[rq * 4 + 1] * linv + 1e-9f * vs4.y;
            ov.z = o[rq * 4 + 2] * linv + 1e-9f * vs4.z;
            ov.w = o[rq * 4 + 3] * linv + 1e-9f * vs4.w;
            *(float4*)&cp[d0] = ov;
        }
    }
}

// ---------------------------------------------------------------------------
template <bool WB>
__global__ __launch_bounds__(256)
void add_ln_kernel(const float* __restrict__ A, const float* __restrict__ Bv,
                   const float* __restrict__ gamma, const float* __restrict__ beta,
                   float* __restrict__ out, ushort_t* __restrict__ outb)
{
    const int row = blockIdx.x;
    const int tid = threadIdx.x;
    const float* a = A  + (size_t)row * H_;
    const float* b = Bv + (size_t)row * H_;

    float4 av = *(const float4*)&a[tid * 4];
    float4 bv = *(const float4*)&b[tid * 4];
    float x[4] = { av.x + bv.x, av.y + bv.y, av.z + bv.z, av.w + bv.w };

    float s  = x[0] + x[1] + x[2] + x[3];
    float s2 = x[0]*x[0] + x[1]*x[1] + x[2]*x[2] + x[3]*x[3];
#pragma unroll
    for (int off = 1; off < 64; off <<= 1) {
        s  += __shfl_xor(s,  off);
        s2 += __shfl_xor(s2, off);
    }
    __shared__ float rs[8];
    const int wave = tid >> 6, lane = tid & 63;
    if (lane == 0) { rs[wave] = s; rs[4 + wave] = s2; }
    __syncthreads();
    const float sum  = rs[0] + rs[1] + rs[2] + rs[3];
    const float sum2 = rs[4] + rs[5] + rs[6] + rs[7];
    const float mu   = sum * (1.f / H_);
    const float var  = sum2 * (1.f / H_) - mu * mu;
    const float rstd = rsqrtf(var + 1e-12f);

    float4 gv = *(const float4*)&gamma[tid * 4];
    float4 be = *(const float4*)&beta[tid * 4];
    float4 ov;
    ov.x = (x[0] - mu) * rstd * gv.x + be.x;
    ov.y = (x[1] - mu) * rstd * gv.y + be.y;
    ov.z = (x[2] - mu) * rstd * gv.z + be.z;
    ov.w = (x[3] - mu) * rstd * gv.w + be.w;
    *(float4*)&out[(size_t)row * H_ + tid * 4] = ov;
    if (WB) {
        ushort4 ob;
        ob.x = f2bf(ov.x); ob.y = f2bf(ov.y); ob.z = f2bf(ov.z); ob.w = f2bf(ov.w);
        *(ushort4*)&outb[(size_t)row * H_ + tid * 4] = ob;
    }
}

// ---------------------------------------------------------------------------
extern "C" void kernel_launch(void* const* d_in, const int* in_sizes, int n_in,
                              void* d_out, int out_size, void* d_ws, size_t ws_size,
                              hipStream_t stream)
{
    const float* hidden = (const float*)d_in[0];
    const float* Wq     = (const float*)d_in[1];
    const float* bq     = (const float*)d_in[2];
    const float* Wk     = (const float*)d_in[3];
    const float* bk     = (const float*)d_in[4];
    const float* Wv     = (const float*)d_in[5];
    const float* bv     = (const float*)d_in[6];
    const float* ln1_g  = (const float*)d_in[7];
    const float* ln1_b  = (const float*)d_in[8];
    const float* W1     = (const float*)d_in[9];
    const float* b1     = (const float*)d_in[10];
    const float* W2     = (const float*)d_in[11];
    const float* b2     = (const float*)d_in[12];
    const float* ln2_g  = (const float*)d_in[13];
    const float* ln2_b  = (const float*)d_in[14];

    char* ws = (char*)d_ws;
    const size_t MB = 1024 * 1024;
    ushort_t* Xb    = (ushort_t*)(ws + 0);
    ushort_t* x1b   = (ushort_t*)(ws + 0);
    ushort_t* Wqt   = (ushort_t*)(ws + 16 * MB);   // Wqt|Wkt|Wvt contiguous
    ushort_t* Wkt   = (ushort_t*)(ws + 18 * MB);
    ushort_t* Wvt   = (ushort_t*)(ws + 20 * MB);
    ushort_t* W1t   = (ushort_t*)(ws + 16 * MB);
    ushort_t* W2t   = (ushort_t*)(ws + 24 * MB);
    ushort_t* q     = (ushort_t*)(ws + 32 * MB);   // q|k|vt contiguous
    ushort_t* k     = (ushort_t*)(ws + 48 * MB);
    ushort_t* vt    = (ushort_t*)(ws + 64 * MB);
    float*    ctx   = (float*)(ws + 80 * MB);
    ushort_t* inter = (ushort_t*)(ws + 32 * MB);
    float*    bcat  = (float*)(ws + 96 * MB);          // dead before out2
    float*    vsum  = (float*)(ws + 96 * MB + 16384);  // dead before out2
    float*    out2  = (float*)(ws + 96 * MB);
    float*    x1    = (float*)(ws + 128 * MB);
    float*    out   = (float*)d_out;

    const dim3 blk(256);

    // 0. casts / prep
    cast_bf16_kernel<<<dim3(BS_ * H_ / 1024), blk, 0, stream>>>(hidden, Xb);
    cast_transpose_kernel<<<dim3(32, 32),  blk, 0, stream>>>(Wq, Wqt, H_, H_);
    cast_transpose_kernel<<<dim3(32, 32),  blk, 0, stream>>>(Wk, Wkt, H_, H_);
    cast_transpose_kernel<<<dim3(32, 32),  blk, 0, stream>>>(Wv, Wvt, H_, H_);
    cast_transpose_kernel<<<dim3(32, 128), blk, 0, stream>>>(W2, W2t, FF_, H_);
    concat3_kernel<<<dim3(12), blk, 0, stream>>>(bq, bk, bv, bcat);

    // 1. fused QKV projection: [q | k | v^T], q pre-scaled by log2(e)/8
    bgemm_kernel<EPI_QKV3><<<dim3(24, 64), blk, 0, stream>>>(
        Xb, Wqt, bcat, q, BS_, 3 * H_, H_, H_, H_);

    // 2. W1 transpose (Wqt region now free)
    cast_transpose_kernel<<<dim3(128, 32), blk, 0, stream>>>(W1, W1t, H_, FF_);

    // 3. V column sums (rows of V^T)
    vsum_kernel<<<dim3(B_ * NH_), blk, 0, stream>>>(vt, vsum);

    // 4. attention (1024 blocks = 16 q-tiles x 64 bh, XCD-swizzled)
    flash_kernel<<<dim3((S_ / 128) * (B_ * NH_)), blk, 0, stream>>>(q, k, vt, vsum, ctx);

    // 5. x1 = LN1(hidden + ctx), + bf16 copy
    add_ln_kernel<true><<<dim3(BS_), blk, 0, stream>>>(hidden, ctx, ln1_g, ln1_b, x1, x1b);

    // 6. inter = gelu(x1 @ W1 + b1) bf16
    bgemm_kernel<EPI_GELU><<<dim3(32, 64), blk, 0, stream>>>(
        x1b, W1t, b1, inter, BS_, FF_, H_, H_, H_);

    // 7. out2 = inter @ W2 + b2 fp32
    bgemm_kernel<EPI_NONE><<<dim3(8, 64), blk, 0, stream>>>(
        inter, W2t, b2, out2, BS_, H_, FF_, FF_, FF_);

    // 8. d_out = LN2(out2 + x1)
    add_ln_kernel<false><<<dim3(BS_), blk, 0, stream>>>(out2, x1, ln2_g, ln2_b, out, nullptr);
}